// Round 5
// baseline (352.194 us; speedup 1.0000x reference)
//
#include <hip/hip_runtime.h>

// Problem constants (match reference)
#define TT 20      // timesteps
#define GG 1024    // groups
#define PP 64      // pedestrians per group
#define THR 0.25f

// LDS-only barrier (no vmcnt drain). Only 2 per block, around staging.
#define BARRIER_LDS() asm volatile("s_waitcnt lgkmcnt(0)\n\ts_barrier" ::: "memory")

// grid = 2*GG blocks, 256 threads; block does half a group (32 i-rows),
// wave w owns rows i = half*32 + c*4 + w, c = 0..7. Fully wave-private
// main loop (NO barriers):
//   - lane l holds ped l's whole trajectory in regs (xj[20] float2)
//   - xi = v_readlane(xj[t], i): wave-uniform i -> SGPR broadcast, no LDS
//   - per row: 20 costs -> swizzled wave-private LDS transpose slice
//     (pi(m) = (m&~7)|((5m)&7); both stride-5 writer and stride-1 reader
//     b128s hit each 4-bank group exactly 2x per 16-lane phase = free)
//   - read back lane-contiguous float4 -> 1 KB/wave global stores
//   - writer==reader wave: in-order DS pipe => no barrier, no WAR hazard
// LDS = one 20480 B buffer; staging area (first 10240 B) aliases it, so
// occupancy is VGPR-capped, not LDS-capped.
__global__ __launch_bounds__(256, 6) void traj_critic_kernel(
    const float* __restrict__ traj, float* __restrict__ out)
{
    __shared__ float4 buf[1280];   // 20480 B; first 640 double as staging xs

    const int blk  = blockIdx.x;
    const int g    = blk >> 1;
    const int half = blk & 1;
    const int tid  = threadIdx.x;
    const int lane = tid & 63;
    const int wid  = tid >> 6;

    // ---- stage group's (T,P,2) f32 -> LDS, layout [t][p] float2, no pad ----
    {
        const float4* tg = (const float4*)traj;
        for (int u = tid; u < 640; u += 256) {
            int t = u >> 5;            // 32 float4 per timestep row
            int r = u & 31;
            buf[u] = tg[t * 32768 + g * 32 + r];
        }
    }
    BARRIER_LDS();

    // per-lane trajectory of ped j = lane (40 VGPRs); contiguous 512B reads
    float2 xj[TT];
    const float2* xs2 = (const float2*)buf;
#pragma unroll
    for (int t = 0; t < TT; ++t) xj[t] = xs2[t * 64 + lane];
    BARRIER_LDS();   // all waves done reading staging before buf overwrite

    const int wbase = wid * 320;                    // wave-private float4 slice
    float4* outg4 = (float4*)out + (size_t)g * 20480;

#pragma unroll 1
    for (int c = 0; c < 8; ++c) {
        const int i = half * 32 + c * 4 + wid;      // this wave's row
        const float kill = (i == lane) ? 0.0f : 1.0f;

        float cst[TT];
#pragma unroll
        for (int t = 0; t < TT; ++t) {
            float xix = __int_as_float(
                __builtin_amdgcn_readlane(__float_as_int(xj[t].x), i));
            float xiy = __int_as_float(
                __builtin_amdgcn_readlane(__float_as_int(xj[t].y), i));
            float dx = xix - xj[t].x;
            float dy = xiy - xj[t].y;
            float d  = __builtin_amdgcn_sqrtf(dx * dx + dy * dy);
            float v  = THR - d;
            v = v > 0.0f ? v : 0.0f;
            cst[t] = v * kill;                      // diagonal -> 0
        }

        // swizzled wave-private transpose: 5x ds_write_b128, conflict-free
#pragma unroll
        for (int kt = 0; kt < 5; ++kt) {
            int m  = wbase + 5 * lane + kt;
            int pm = (m & ~7) | ((5 * m) & 7);
            buf[pm] = make_float4(cst[4 * kt + 0], cst[4 * kt + 1],
                                  cst[4 * kt + 2], cst[4 * kt + 3]);
        }

        // same-wave read-back (in-order DS => visible, no barrier) + store
        float4* op = outg4 + (size_t)i * 320;
#pragma unroll
        for (int k = 0; k < 5; ++k) {
            int m  = wbase + k * 64 + lane;
            int pm = (m & ~7) | ((5 * m) & 7);
            op[k * 64 + lane] = buf[pm];
        }
    }
}

extern "C" void kernel_launch(void* const* d_in, const int* in_sizes, int n_in,
                              void* d_out, int out_size, void* d_ws, size_t ws_size,
                              hipStream_t stream) {
    const float* traj = (const float*)d_in[0];  // (T, B, 2) f32
    float* out = (float*)d_out;                 // G*P*P*T f32
    traj_critic_kernel<<<2 * GG, 256, 0, stream>>>(traj, out);
}

// Round 6
// 351.167 us; speedup vs baseline: 1.0029x; 1.0029x over previous
//
#include <hip/hip_runtime.h>

// Problem constants (match reference)
#define TT 20      // timesteps
#define GG 1024    // groups
#define PP 64      // pedestrians per group
#define THR 0.25f

// LDS-only barrier (no vmcnt drain). Only 2 per block, around staging.
#define BARRIER_LDS() asm volatile("s_waitcnt lgkmcnt(0)\n\ts_barrier" ::: "memory")

// grid = 2*GG blocks, 256 threads; block does half a group (32 i-rows),
// wave w owns rows i = half*32 + c*4 + w, c = 0..7.
//
// R5 structure (wave-private, barrier-free main loop, readlane broadcast,
// swizzled in-LDS transpose) + ONE change: the row loop is software-
// pipelined one row deep. Per iteration:
//     compute cst[c+1]          (~450 cyc VALU, no DS)
//     lgkm-wait + store pend[c] (DS round-trip of row c hidden under compute)
//     ds_write cst[c+1]; ds_read -> pend[c+1]   (latency hides under next iter)
// In-order per-wave DS pipe makes same-slice read-after-write and
// write-after-read correct without barriers.
__global__ __launch_bounds__(256) void traj_critic_kernel(
    const float* __restrict__ traj, float* __restrict__ out)
{
    __shared__ float4 buf[1280];   // 20480 B; first 640 double as staging

    const int blk  = blockIdx.x;
    const int g    = blk >> 1;
    const int half = blk & 1;
    const int tid  = threadIdx.x;
    const int lane = tid & 63;
    const int wid  = tid >> 6;

    // ---- stage group's (T,P,2) f32 -> LDS, layout [t][p] float2 ----
    {
        const float4* tg = (const float4*)traj;
        for (int u = tid; u < 640; u += 256) {
            int t = u >> 5;            // 32 float4 per timestep row
            int r = u & 31;
            buf[u] = tg[t * 32768 + g * 32 + r];
        }
    }
    BARRIER_LDS();

    // per-lane trajectory of ped j = lane (40 VGPRs)
    float2 xj[TT];
    const float2* xs2 = (const float2*)buf;
#pragma unroll
    for (int t = 0; t < TT; ++t) xj[t] = xs2[t * 64 + lane];
    BARRIER_LDS();   // all waves done reading staging before buf overwrite

    const int wbase = wid * 320;                    // wave-private float4 slice
    float4* outg4 = (float4*)out + (size_t)g * 20480;

    float cst[TT];
    float4 pend[5];

    // ---- compute one row's 20 costs into cst ----
#define COMPUTE_ROW(C)                                                        \
    {                                                                         \
        const int i = half * 32 + (C) * 4 + wid;                              \
        const float kill = (i == lane) ? 0.0f : 1.0f;                         \
        _Pragma("unroll")                                                     \
        for (int t = 0; t < TT; ++t) {                                        \
            float xix = __int_as_float(                                       \
                __builtin_amdgcn_readlane(__float_as_int(xj[t].x), i));       \
            float xiy = __int_as_float(                                       \
                __builtin_amdgcn_readlane(__float_as_int(xj[t].y), i));       \
            float dx = xix - xj[t].x;                                         \
            float dy = xiy - xj[t].y;                                         \
            float d  = __builtin_amdgcn_sqrtf(dx * dx + dy * dy);             \
            float v  = THR - d;                                               \
            v = v > 0.0f ? v : 0.0f;                                          \
            cst[t] = v * kill;                                                \
        }                                                                     \
    }

    // ---- swizzled transpose write + read-back issue (no wait here) ----
#define DS_ROUNDTRIP()                                                        \
    {                                                                         \
        _Pragma("unroll")                                                     \
        for (int kt = 0; kt < 5; ++kt) {                                      \
            int m  = wbase + 5 * lane + kt;                                   \
            int pm = (m & ~7) | ((5 * m) & 7);                                \
            buf[pm] = make_float4(cst[4 * kt + 0], cst[4 * kt + 1],           \
                                  cst[4 * kt + 2], cst[4 * kt + 3]);          \
        }                                                                     \
        _Pragma("unroll")                                                     \
        for (int k = 0; k < 5; ++k) {                                         \
            int m  = wbase + k * 64 + lane;                                   \
            int pm = (m & ~7) | ((5 * m) & 7);                                \
            pend[k] = buf[pm];                                                \
        }                                                                     \
    }

    // prologue: row 0
    COMPUTE_ROW(0);
    DS_ROUNDTRIP();

#pragma unroll
    for (int c = 0; c < 8; ++c) {
        if (c < 7) COMPUTE_ROW(c + 1);   // VALU hides row c's DS latency

        // store row c (compiler places lgkm wait here, after the compute)
        const int irow = half * 32 + c * 4 + wid;
        float4* op = outg4 + (size_t)irow * 320;
#pragma unroll
        for (int k = 0; k < 5; ++k) op[k * 64 + lane] = pend[k];

        if (c < 7) DS_ROUNDTRIP();       // issue next row's transpose
    }
#undef COMPUTE_ROW
#undef DS_ROUNDTRIP
}

extern "C" void kernel_launch(void* const* d_in, const int* in_sizes, int n_in,
                              void* d_out, int out_size, void* d_ws, size_t ws_size,
                              hipStream_t stream) {
    const float* traj = (const float*)d_in[0];  // (T, B, 2) f32
    float* out = (float*)d_out;                 // G*P*P*T f32
    traj_critic_kernel<<<2 * GG, 256, 0, stream>>>(traj, out);
}

// Round 8
// 348.303 us; speedup vs baseline: 1.0112x; 1.0082x over previous
//
#include <hip/hip_runtime.h>

// Problem constants (match reference)
#define TT 20      // timesteps
#define GG 1024    // groups
#define PP 64      // pedestrians per group
#define THR 0.25f

// native clang vector (HIP's float4 is a class; the nontemporal builtin
// requires a scalar/native-vector type)
typedef float f32x4 __attribute__((ext_vector_type(4)));

// LDS-only barrier (no vmcnt drain). Only 2 per block, around staging.
#define BARRIER_LDS() asm volatile("s_waitcnt lgkmcnt(0)\n\ts_barrier" ::: "memory")

// grid = 2*GG blocks, 256 threads; block does half a group (32 i-rows),
// wave w owns rows i = half*32 + c*4 + w, c = 0..7. Wave-private main loop
// (no barriers): lane l holds ped l's trajectory in regs; xi via readlane
// (SGPR broadcast); swizzled in-LDS transpose (pi(m)=(m&~7)|((5m)&7), both
// sides conflict-free b128); lane-contiguous 1KB wave stores.
//
// R7: output stores are NONTEMPORAL (global_store_dwordx4 ... nt).
// The 335 MB output is write-once never-read and >> L2: plain stores
// allocate dirty L2 lines that must later be evicted (XCD write path paid
// twice, eviction competing with incoming stores). nt streams past L2 —
// plausibly how the runtime fill kernel reaches 6.2 TB/s.
__global__ __launch_bounds__(256) void traj_critic_kernel(
    const float* __restrict__ traj, float* __restrict__ out)
{
    __shared__ float4 buf[1280];   // 20480 B; first 640 double as staging

    const int blk  = blockIdx.x;
    const int g    = blk >> 1;
    const int half = blk & 1;
    const int tid  = threadIdx.x;
    const int lane = tid & 63;
    const int wid  = tid >> 6;

    // ---- stage group's (T,P,2) f32 -> LDS, layout [t][p] float2 ----
    {
        const float4* tg = (const float4*)traj;
        for (int u = tid; u < 640; u += 256) {
            int t = u >> 5;            // 32 float4 per timestep row
            int r = u & 31;
            buf[u] = tg[t * 32768 + g * 32 + r];
        }
    }
    BARRIER_LDS();

    // per-lane trajectory of ped j = lane (40 VGPRs)
    float2 xj[TT];
    const float2* xs2 = (const float2*)buf;
#pragma unroll
    for (int t = 0; t < TT; ++t) xj[t] = xs2[t * 64 + lane];
    BARRIER_LDS();   // all waves done reading staging before buf overwrite

    const int wbase = wid * 320;                    // wave-private float4 slice
    f32x4* outg4 = (f32x4*)out + (size_t)g * 20480;

#pragma unroll 1
    for (int c = 0; c < 8; ++c) {
        const int i = half * 32 + c * 4 + wid;      // this wave's row
        const float kill = (i == lane) ? 0.0f : 1.0f;

        float cst[TT];
#pragma unroll
        for (int t = 0; t < TT; ++t) {
            float xix = __int_as_float(
                __builtin_amdgcn_readlane(__float_as_int(xj[t].x), i));
            float xiy = __int_as_float(
                __builtin_amdgcn_readlane(__float_as_int(xj[t].y), i));
            float dx = xix - xj[t].x;
            float dy = xiy - xj[t].y;
            float d  = __builtin_amdgcn_sqrtf(dx * dx + dy * dy);
            float v  = THR - d;
            v = v > 0.0f ? v : 0.0f;
            cst[t] = v * kill;                      // diagonal -> 0
        }

        // swizzled wave-private transpose: 5x ds_write_b128, conflict-free
#pragma unroll
        for (int kt = 0; kt < 5; ++kt) {
            int m  = wbase + 5 * lane + kt;
            int pm = (m & ~7) | ((5 * m) & 7);
            buf[pm] = make_float4(cst[4 * kt + 0], cst[4 * kt + 1],
                                  cst[4 * kt + 2], cst[4 * kt + 3]);
        }

        // same-wave read-back + NONTEMPORAL lane-contiguous stores
        f32x4* op = outg4 + (size_t)i * 320;
#pragma unroll
        for (int k = 0; k < 5; ++k) {
            int m  = wbase + k * 64 + lane;
            int pm = (m & ~7) | ((5 * m) & 7);
            float4 v = buf[pm];
            f32x4 nv = { v.x, v.y, v.z, v.w };
            __builtin_nontemporal_store(nv, &op[k * 64 + lane]);
        }
    }
}

extern "C" void kernel_launch(void* const* d_in, const int* in_sizes, int n_in,
                              void* d_out, int out_size, void* d_ws, size_t ws_size,
                              hipStream_t stream) {
    const float* traj = (const float*)d_in[0];  // (T, B, 2) f32
    float* out = (float*)d_out;                 // G*P*P*T f32
    traj_critic_kernel<<<2 * GG, 256, 0, stream>>>(traj, out);
}